// Round 3
// baseline (279.704 us; speedup 1.0000x reference)
//
#include <hip/hip_runtime.h>
#include <hip/hip_bf16.h>
#include <stdint.h>

// B=8, L=4096, T=512, D_H=1280, D_G=768, D_P=256, scale = 1/16

typedef float f32x4 __attribute__((ext_vector_type(4)));
typedef short bf16x8 __attribute__((ext_vector_type(8)));

__device__ __forceinline__ unsigned short f2bf(float f) {
    __hip_bfloat16 h = __float2bfloat16(f);   // RNE, hw cvt on gfx950
    return __builtin_bit_cast(unsigned short, h);
}
__device__ __forceinline__ float bf2f(unsigned short h) {
    union { uint32_t u; float f; } v; v.u = ((uint32_t)h) << 16;
    return v.f;
}

// XCD-chunk swizzle (bijective; gridDim.x % 8 == 0 at all call sites)
__device__ __forceinline__ int xcdswz(int bx, int nbx) {
    int cpx = nbx >> 3;
    return (bx & 7) * cpx + (bx >> 3);
}

// async global->LDS, 16B per lane. LDS dest is wave-uniform base + lane*16.
__device__ __forceinline__ void gload16(const unsigned short* g, unsigned short* l) {
    __builtin_amdgcn_global_load_lds(
        (const __attribute__((address_space(1))) void*)g,
        (__attribute__((address_space(3))) void*)l,
        16, 0, 0);
}

// LDS addressing for the f32-staged projection GEMM (legacy path)
__device__ __forceinline__ int lidx(int row, int kshort) {
    return row * 40 + (((kshort >> 3) ^ ((row >> 3) & 3)) << 3) + (kshort & 7);
}

// ---------------------------------------------------------------------------
// Projection GEMM: C[m,n] = scale * sum_k A[m,k]*B[n,k], f32 inputs (cvt to
// bf16 in staging). Tile 128x128, BK=32, 4 waves 2x2. Used for K/Q proj.
// ---------------------------------------------------------------------------
template<bool AF32, bool BF32, bool OBF16, bool TNF>
__global__ __launch_bounds__(256)
void gemm_bt(const void* __restrict__ Ap, const void* __restrict__ Bp,
             void* __restrict__ Cp, int M, int N, int K,
             long sA, long sB, long sC, float scale)
{
    __shared__ __align__(16) unsigned short lA[128 * 40];
    __shared__ __align__(16) unsigned short lB[128 * 40];

    const int bx = xcdswz(blockIdx.x, gridDim.x);
    const int mt = M >> 7, nt = N >> 7;
    const int tm = TNF ? (bx / nt) : (bx % mt);
    const int tn = TNF ? (bx % nt) : (bx / mt);
    const int b  = blockIdx.y;
    const int tid = threadIdx.x;
    const int lane = tid & 63, wv = tid >> 6;
    const int wr = wv >> 1, wc = wv & 1;
    const int fr = lane & 15, fk = lane >> 4;

    f32x4 acc[4][4] = {};

    const char* Abase = (const char*)Ap;
    const char* Bbase = (const char*)Bp;

    for (int k0 = 0; k0 < K; k0 += 32) {
        if constexpr (AF32) {
            const float* A = (const float*)Abase + (long)b * sA + (long)tm * 128 * K + k0;
            #pragma unroll
            for (int it = 0; it < 4; ++it) {
                int chunk = it * 256 + tid;
                int row = chunk >> 3;
                int kc  = (chunk & 7) << 2;
                const float4 v = *(const float4*)(A + (long)row * K + kc);
                ushort4 w;
                w.x = f2bf(v.x); w.y = f2bf(v.y); w.z = f2bf(v.z); w.w = f2bf(v.w);
                *(ushort4*)(&lA[lidx(row, kc)]) = w;
            }
        } else {
            const unsigned short* A = (const unsigned short*)Abase + (long)b * sA + (long)tm * 128 * K + k0;
            #pragma unroll
            for (int it = 0; it < 2; ++it) {
                int chunk = it * 256 + tid;
                int row = chunk >> 2;
                int kc  = (chunk & 3) << 3;
                *(uint4*)(&lA[lidx(row, kc)]) = *(const uint4*)(A + (long)row * K + kc);
            }
        }
        if constexpr (BF32) {
            const float* B = (const float*)Bbase + (long)b * sB + (long)tn * 128 * K + k0;
            #pragma unroll
            for (int it = 0; it < 4; ++it) {
                int chunk = it * 256 + tid;
                int row = chunk >> 3;
                int kc  = (chunk & 7) << 2;
                const float4 v = *(const float4*)(B + (long)row * K + kc);
                ushort4 w;
                w.x = f2bf(v.x); w.y = f2bf(v.y); w.z = f2bf(v.z); w.w = f2bf(v.w);
                *(ushort4*)(&lB[lidx(row, kc)]) = w;
            }
        } else {
            const unsigned short* B = (const unsigned short*)Bbase + (long)b * sB + (long)tn * 128 * K + k0;
            #pragma unroll
            for (int it = 0; it < 2; ++it) {
                int chunk = it * 256 + tid;
                int row = chunk >> 2;
                int kc  = (chunk & 3) << 3;
                *(uint4*)(&lB[lidx(row, kc)]) = *(const uint4*)(B + (long)row * K + kc);
            }
        }
        __syncthreads();
        bf16x8 af[4], bfr[4];
        #pragma unroll
        for (int i = 0; i < 4; ++i)
            af[i] = *(const bf16x8*)(&lA[lidx(wr * 64 + i * 16 + fr, fk * 8)]);
        #pragma unroll
        for (int i = 0; i < 4; ++i)
            bfr[i] = *(const bf16x8*)(&lB[lidx(wc * 64 + i * 16 + fr, fk * 8)]);
        #pragma unroll
        for (int mi = 0; mi < 4; ++mi)
            #pragma unroll
            for (int ni = 0; ni < 4; ++ni)
                acc[mi][ni] = __builtin_amdgcn_mfma_f32_16x16x32_bf16(af[mi], bfr[ni], acc[mi][ni], 0, 0, 0);
        __syncthreads();
    }

    if constexpr (OBF16) {
        unsigned short* C = (unsigned short*)Cp + (long)b * sC + ((long)tm * 128) * N + (long)tn * 128;
        #pragma unroll
        for (int mi = 0; mi < 4; ++mi)
            #pragma unroll
            for (int ni = 0; ni < 4; ++ni)
                #pragma unroll
                for (int j = 0; j < 4; ++j) {
                    int m = wr * 64 + mi * 16 + fk * 4 + j;
                    int n = wc * 64 + ni * 16 + fr;
                    C[(long)m * N + n] = f2bf(acc[mi][ni][j] * scale);
                }
    } else {
        float* C = (float*)Cp + (long)b * sC + ((long)tm * 128) * N + (long)tn * 128;
        #pragma unroll
        for (int mi = 0; mi < 4; ++mi)
            #pragma unroll
            for (int ni = 0; ni < 4; ++ni)
                #pragma unroll
                for (int j = 0; j < 4; ++j) {
                    int m = wr * 64 + mi * 16 + fk * 4 + j;
                    int n = wc * 64 + ni * 16 + fr;
                    C[(long)m * N + n] = acc[mi][ni][j] * scale;
                }
    }
}

// ---------------------------------------------------------------------------
// All-bf16 C = scale * A @ B^T, m97 recipe: global_load_lds width-16 staging
// into linear LDS [rows][32], BK=32, 4 waves 2x2. Tile 128 x TN (TN=128|64).
// ---------------------------------------------------------------------------
template<int TN, bool OBF16>
__global__ __launch_bounds__(256)
void gemm_bt16(const unsigned short* __restrict__ Ap, const unsigned short* __restrict__ Bp,
               void* __restrict__ Cp, int M, int N, int K,
               long sA, long sB, long sC, float scale)
{
    constexpr int NB = TN / 32;       // B frags per wave
    constexpr int BISS = TN / 64;     // B gload issues per thread
    __shared__ __align__(16) unsigned short lA[128 * 32];
    __shared__ __align__(16) unsigned short lB[TN * 32];

    const int bx = xcdswz(blockIdx.x, gridDim.x);
    const int mt = M >> 7;
    const int tm = bx % mt, tn = bx / mt;
    const int b  = blockIdx.y;
    const int tid = threadIdx.x;
    const int lane = tid & 63, wv = tid >> 6;
    const int wr = wv >> 1, wc = wv & 1;
    const int fr = lane & 15, fk = lane >> 4;

    f32x4 acc[4][NB] = {};

    const unsigned short* A0 = Ap + (long)b * sA + (long)tm * 128 * K;
    const unsigned short* B0 = Bp + (long)b * sB + (long)tn * TN * K;

    for (int k0 = 0; k0 < K; k0 += 32) {
        // A: 128x32 bf16 = 512 slots of 16B; 2 issues/thread
        #pragma unroll
        for (int q = 0; q < 2; ++q) {
            int slot = wv * 128 + q * 64 + lane;
            int row = slot >> 2, kc = (slot & 3) << 3;
            gload16(A0 + (long)row * K + k0 + kc, lA + (size_t)(wv * 128 + q * 64) * 8);
        }
        // B: TN x 32 bf16 = TN*4 slots; BISS issues/thread
        #pragma unroll
        for (int q = 0; q < BISS; ++q) {
            int slot = wv * (BISS * 64) + q * 64 + lane;
            int row = slot >> 2, kc = (slot & 3) << 3;
            gload16(B0 + (long)row * K + k0 + kc, lB + (size_t)(wv * (BISS * 64) + q * 64) * 8);
        }
        __syncthreads();
        bf16x8 af[4], bfv[NB];
        #pragma unroll
        for (int i = 0; i < 4; ++i)
            af[i] = *(const bf16x8*)(lA + (wr * 64 + i * 16 + fr) * 32 + fk * 8);
        #pragma unroll
        for (int i = 0; i < NB; ++i)
            bfv[i] = *(const bf16x8*)(lB + (wc * (TN / 2) + i * 16 + fr) * 32 + fk * 8);
        #pragma unroll
        for (int mi = 0; mi < 4; ++mi)
            #pragma unroll
            for (int ni = 0; ni < NB; ++ni)
                acc[mi][ni] = __builtin_amdgcn_mfma_f32_16x16x32_bf16(af[mi], bfv[ni], acc[mi][ni], 0, 0, 0);
        __syncthreads();
    }

    if constexpr (OBF16) {
        unsigned short* C = (unsigned short*)Cp + (long)b * sC + ((long)tm * 128) * N + (long)tn * TN;
        #pragma unroll
        for (int mi = 0; mi < 4; ++mi)
            #pragma unroll
            for (int ni = 0; ni < NB; ++ni)
                #pragma unroll
                for (int j = 0; j < 4; ++j) {
                    int m = wr * 64 + mi * 16 + fk * 4 + j;
                    int n = wc * (TN / 2) + ni * 16 + fr;
                    C[(long)m * N + n] = f2bf(acc[mi][ni][j] * scale);
                }
    } else {
        float* C = (float*)Cp + (long)b * sC + ((long)tm * 128) * N + (long)tn * TN;
        #pragma unroll
        for (int mi = 0; mi < 4; ++mi)
            #pragma unroll
            for (int ni = 0; ni < NB; ++ni)
                #pragma unroll
                for (int j = 0; j < 4; ++j) {
                    int m = wr * 64 + mi * 16 + fk * 4 + j;
                    int n = wc * (TN / 2) + ni * 16 + fr;
                    C[(long)m * N + n] = acc[mi][ni][j] * scale;
                }
    }
}

// ---------------------------------------------------------------------------
// H [8][4096][1280] f32 -> Hbt [8][1280][4096] bf16 (transpose + convert).
// 64x64 tiles via LDS; 16-short-granule XOR swizzle breaks bank conflicts.
// ---------------------------------------------------------------------------
__global__ __launch_bounds__(256)
void transpose_h(const float* __restrict__ H, unsigned short* __restrict__ Hbt)
{
    __shared__ unsigned short lT[64 * 72];
    const int ntile = 64 * 20 * 8;
    for (int tileid = blockIdx.x; tileid < ntile; tileid += gridDim.x) {
        int tmp = tileid;
        const int dt = tmp % 20; tmp /= 20;
        const int lt = tmp % 64;
        const int b  = tmp / 64;
        const int l0 = lt * 64, d0 = dt * 64;
        const float* Hs = H + ((long)b * 4096 + l0) * 1280 + d0;
        #pragma unroll
        for (int it = 0; it < 4; ++it) {
            int chunk = it * 256 + threadIdx.x;      // 1024 chunks
            int lr = chunk >> 4, dc4 = (chunk & 15) << 2;
            float4 v = *(const float4*)(Hs + (long)lr * 1280 + dc4);
            unsigned short w[4] = { f2bf(v.x), f2bf(v.y), f2bf(v.z), f2bf(v.w) };
            #pragma unroll
            for (int j = 0; j < 4; ++j) {
                int d = dc4 + j;
                int sl = (lr & 15) | ((((lr >> 4) ^ (d >> 2)) & 3) << 4);
                lT[d * 72 + sl] = w[j];
            }
        }
        __syncthreads();
        {
            int drow = threadIdx.x >> 2, lc = threadIdx.x & 3;
            int slc = lc ^ ((drow >> 2) & 3);
            const uint4* src = (const uint4*)(lT + drow * 72 + slc * 16);
            unsigned short* dst = Hbt + ((long)b * 1280 + d0 + drow) * 4096 + l0 + lc * 16;
            uint4 v0 = src[0], v1 = src[1];
            *(uint4*)(dst)     = v0;
            *(uint4*)(dst + 8) = v1;
        }
        __syncthreads();
    }
}

// ---------------------------------------------------------------------------
// Fallback Z-GEMM (round-2 path) when workspace can't hold Hbt.
// ---------------------------------------------------------------------------
__global__ __launch_bounds__(256)
void gemm_kn(const unsigned short* __restrict__ Ap, const float* __restrict__ Bp,
             float* __restrict__ Cp, int M, int N, int K,
             long sA, long sB, long sC)
{
    __shared__ __align__(16) unsigned short lA[128 * 40];
    __shared__ __align__(16) unsigned short lB[64 * 40];

    const int bx = xcdswz(blockIdx.x, gridDim.x);
    const int mt = M >> 7;
    const int tm = bx % mt;
    const int tn = bx / mt;
    const int b  = blockIdx.y;
    const int tid = threadIdx.x;
    const int lane = tid & 63, wv = tid >> 6;
    const int wr = wv >> 1, wc = wv & 1;
    const int fr = lane & 15, fk = lane >> 4;

    f32x4 acc[4][2] = {};

    const unsigned short* A0 = Ap + (long)b * sA + (long)tm * 128 * K;
    const int nn    = tid & 63;
    const int khalf = tid >> 6;

    for (int k0 = 0; k0 < K; k0 += 32) {
        #pragma unroll
        for (int it = 0; it < 2; ++it) {
            int chunk = it * 256 + tid;
            int row = chunk >> 2;
            int kc  = (chunk & 3) << 3;
            *(uint4*)(&lA[lidx(row, kc)]) = *(const uint4*)(A0 + (long)row * K + k0 + kc);
        }
        {
            const float* Bb = Bp + (long)b * sB + (long)(k0 + khalf * 8) * N + (long)tn * 64 + nn;
            unsigned short t8[8];
            #pragma unroll
            for (int kk = 0; kk < 8; ++kk)
                t8[kk] = f2bf(Bb[(long)kk * N]);
            *(uint4*)(&lB[lidx(nn, khalf * 8)]) = *(uint4*)(&t8[0]);
        }
        __syncthreads();
        bf16x8 af[4], bfr[2];
        #pragma unroll
        for (int i = 0; i < 4; ++i)
            af[i] = *(const bf16x8*)(&lA[lidx(wr * 64 + i * 16 + fr, fk * 8)]);
        #pragma unroll
        for (int i = 0; i < 2; ++i)
            bfr[i] = *(const bf16x8*)(&lB[lidx(wc * 32 + i * 16 + fr, fk * 8)]);
        #pragma unroll
        for (int mi = 0; mi < 4; ++mi)
            #pragma unroll
            for (int ni = 0; ni < 2; ++ni)
                acc[mi][ni] = __builtin_amdgcn_mfma_f32_16x16x32_bf16(af[mi], bfr[ni], acc[mi][ni], 0, 0, 0);
        __syncthreads();
    }

    float* C = Cp + (long)b * sC + ((long)tm * 128) * N + (long)tn * 64;
    #pragma unroll
    for (int mi = 0; mi < 4; ++mi)
        #pragma unroll
        for (int ni = 0; ni < 2; ++ni)
            #pragma unroll
            for (int j = 0; j < 4; ++j) {
                int m = wr * 64 + mi * 16 + fk * 4 + j;
                int n = wc * 32 + ni * 16 + fr;
                C[(long)m * N + n] = acc[mi][ni][j];
            }
}

// ---------------------------------------------------------------------------
// Row softmax in place on S (bf16), rows of length 4096.
// ---------------------------------------------------------------------------
__global__ __launch_bounds__(256)
void softmax_rows(unsigned short* __restrict__ S, const unsigned char* __restrict__ mask)
{
    const int row = blockIdx.x;
    const int b = row >> 9;
    const long base = (long)row * 4096;
    const int tid = threadIdx.x, lane = tid & 63, wv = tid >> 6;
    __shared__ float red[8];

    uint4 s0 = *(const uint4*)(S + base + tid * 16);
    uint4 s1 = *(const uint4*)(S + base + tid * 16 + 8);
    uint4 mv = *(const uint4*)(mask + (long)b * 4096 + tid * 16);
    const unsigned char* mb = (const unsigned char*)&mv;

    unsigned int words[8] = { s0.x, s0.y, s0.z, s0.w, s1.x, s1.y, s1.z, s1.w };
    float x[16];
    #pragma unroll
    for (int i = 0; i < 8; ++i) {
        x[2 * i]     = bf2f((unsigned short)(words[i] & 0xffffu));
        x[2 * i + 1] = bf2f((unsigned short)(words[i] >> 16));
    }
    #pragma unroll
    for (int i = 0; i < 16; ++i)
        if (mb[i]) x[i] = -1e30f;

    float m = x[0];
    #pragma unroll
    for (int i = 1; i < 16; ++i) m = fmaxf(m, x[i]);
    #pragma unroll
    for (int off = 32; off; off >>= 1) m = fmaxf(m, __shfl_xor(m, off));
    if (lane == 0) red[wv] = m;
    __syncthreads();
    m = fmaxf(fmaxf(red[0], red[1]), fmaxf(red[2], red[3]));

    float p[16];
    float s = 0.f;
    #pragma unroll
    for (int i = 0; i < 16; ++i) { p[i] = __expf(x[i] - m); s += p[i]; }
    #pragma unroll
    for (int off = 32; off; off >>= 1) s += __shfl_xor(s, off);
    if (lane == 0) red[4 + wv] = s;
    __syncthreads();
    s = (red[4] + red[5]) + (red[6] + red[7]);
    const float inv = 1.0f / s;

    unsigned int ow[8];
    #pragma unroll
    for (int i = 0; i < 8; ++i) {
        unsigned int lo = f2bf(p[2 * i] * inv);
        unsigned int hi = f2bf(p[2 * i + 1] * inv);
        ow[i] = lo | (hi << 16);
    }
    uint4 o0 = { ow[0], ow[1], ow[2], ow[3] };
    uint4 o1 = { ow[4], ow[5], ow[6], ow[7] };
    *(uint4*)(S + base + tid * 16)     = o0;
    *(uint4*)(S + base + tid * 16 + 8) = o1;
}

// ---------------------------------------------------------------------------
extern "C" void kernel_launch(void* const* d_in, const int* in_sizes, int n_in,
                              void* d_out, int out_size, void* d_ws, size_t ws_size,
                              hipStream_t stream)
{
    const float*         H    = (const float*)d_in[0];
    const float*         G    = (const float*)d_in[1];
    const unsigned char* mask = (const unsigned char*)d_in[2];
    const float*         Wk   = (const float*)d_in[3];
    const float*         Wq   = (const float*)d_in[4];
    float*               out  = (float*)d_out;

    const long nK = (long)8 * 4096 * 256;   // bf16 elems
    const long nQ = (long)8 * 512 * 256;
    const long nS = (long)8 * 512 * 4096;
    const long nH = (long)8 * 1280 * 4096;

    unsigned short* Kb  = (unsigned short*)d_ws;
    unsigned short* Qb  = Kb + nK;
    unsigned short* Sb  = Qb + nQ;
    unsigned short* Hbt = Sb + nS;
    const bool big = ws_size >= (size_t)(nK + nQ + nS + nH) * 2;

    // 1) K = H @ Wk^T  (M=32768,N=256,K=1280)
    gemm_bt<true, true, true, true><<<dim3(512, 1), 256, 0, stream>>>(
        H, Wk, Kb, 32768, 256, 1280, 0, 0, 0, 1.0f);
    // 2) Q = G @ Wq^T  (M=4096,N=256,K=768)
    gemm_bt<true, true, true, true><<<dim3(64, 1), 256, 0, stream>>>(
        G, Wq, Qb, 4096, 256, 768, 0, 0, 0, 1.0f);

    if (big) {
        // 3) Hbt = transpose(H) in bf16
        transpose_h<<<dim3(2048), 256, 0, stream>>>(H, Hbt);
        // 4) S = Q @ K^T * scale  per batch (M=512,N=4096,K=256)
        gemm_bt16<128, true><<<dim3(128, 8), 256, 0, stream>>>(
            Qb, Kb, Sb, 512, 4096, 256,
            (long)512 * 256, (long)4096 * 256, (long)512 * 4096, 0.0625f);
        // 5) softmax
        softmax_rows<<<dim3(4096), 256, 0, stream>>>(Sb, mask);
        // 6) Z = alpha @ Hbt^T  per batch (M=512,N=1280,K=4096)
        gemm_bt16<64, false><<<dim3(80, 8), 256, 0, stream>>>(
            Sb, Hbt, out, 512, 1280, 4096,
            (long)512 * 4096, (long)1280 * 4096, (long)512 * 1280, 1.0f);
    } else {
        // fallback: round-2 path
        gemm_bt<false, false, true, false><<<dim3(128, 8), 256, 0, stream>>>(
            Qb, Kb, Sb, 512, 4096, 256,
            (long)512 * 256, (long)4096 * 256, (long)512 * 4096, 0.0625f);
        softmax_rows<<<dim3(4096), 256, 0, stream>>>(Sb, mask);
        gemm_kn<<<dim3(80, 8), 256, 0, stream>>>(
            Sb, H, out, 512, 1280, 4096,
            (long)512 * 4096, (long)4096 * 1280, (long)512 * 1280);
    }
}